// Round 12
// baseline (24.778 us; speedup 1.0000x reference)
//
#include <hip/hip_runtime.h>

// SuperResolve: A=4 frames, n=4, c=3, h=w=256, S=2 -> out (4,3,512,512) fp32
// R12 = R8 (best, 23.6us) + v_pk_*_f32 packing of the sx-pair math.
// R4 tested packing in a latency-bound regime (26% occ) -> null was
// uninterpretable. Now ~issue-bound (R10: VMEM count irrelevant; R11: more
// waves irrelevant) -> packing halves VALU issue, the binding resource.
// Scalar Sterbenz-exact dy/dx setup (R9: mask bit-exactness vs numpy).
// pk ops use mul-then-fma = same rounding as R8's scalar fmaf forms.
// R3/R9: never force-cap VGPR. R6: SGPR plane bases. R7: LDS staging loses.
// R8: raw v_exp_f32, q-premask, no dist clamp (max 17.6 < 20).

#define AF      4
#define NB      4
#define CH      3
#define H       256
#define W       256
#define SH      512
#define SW      512
#define HW      (H*W)
#define SHW     (SH*SW)
#define RADIUS  4.0f
// 0.25 (LR displacement scaling) * 0.5*log2(e): weight = exp2(-dist')
#define MSCALE  0.18033688011112042f

typedef float v2f __attribute__((ext_vector_type(2)));

__global__ __launch_bounds__(256) void superresolve_kernel(
    const float* __restrict__ alts,     // [AF][NB][CH][H][W]
    const float* __restrict__ offsets,  // [AF][NB][2][H][W]
    const float* __restrict__ qs,       // [AF][NB][H][W]
    const float* __restrict__ o11,      // [NB][SH][SW]
    const float* __restrict__ o12,
    const float* __restrict__ o21,
    const float* __restrict__ o22,
    float* __restrict__ out)            // [NB][CH][SH][SW]
{
    __shared__ float red[128 * 17];     // stride 17 words: conflict-free

    const int tid   = threadIdx.x;
    const int wv    = tid >> 6;
    const int lane  = tid & 63;
    const int fpair = wv >> 1;                  // 0: frames {0,1}; 1: {2,3}
    const int pix   = ((wv & 1) << 6) + lane;   // 0..127

    // bijective XCD swizzle over 2048 blocks
    const int bid = blockIdx.x;
    const int swz = (bid & 7) * 256 + (bid >> 3);
    const int P   = swz * 128 + pix;            // linear LR pixel id

    const int x0 = P & (W - 1);
    // wave-uniform -> SGPRs
    const int y0  = __builtin_amdgcn_readfirstlane((P >> 8) & (H - 1));
    const int nn  = __builtin_amdgcn_readfirstlane(P >> 16);
    const int af0 = __builtin_amdgcn_readfirstlane(fpair << 1);

    const bool bL = (x0 > 0);
    const bool bR = (x0 < W - 1);
    const int  xL = bL ? x0 - 1 : 0;
    const int  xR = bR ? x0 + 1 : W - 1;
    const int  iL = y0 * W + xL;
    const int  iC = y0 * W + x0;
    const int  iR = y0 * W + xR;
    const float f2xL = (float)(2 * xL);
    const float f2xC = (float)(2 * x0);
    const float f2xR = (float)(2 * xR);
    const float xf0  = f2xC;
    const float yf0  = (float)(2 * y0);

    // per-subpixel o-matrices (float2 loads, coalesced); [sy] over rows,
    // vector lane over sx.
    const int obase = (nn * SH + 2 * y0) * SW + 2 * x0;
    const float2 v11a = *(const float2*)(o11 + obase);
    const float2 v11b = *(const float2*)(o11 + obase + SW);
    const float2 v12a = *(const float2*)(o12 + obase);
    const float2 v12b = *(const float2*)(o12 + obase + SW);
    const float2 v21a = *(const float2*)(o21 + obase);
    const float2 v21b = *(const float2*)(o21 + obase + SW);
    const float2 v22a = *(const float2*)(o22 + obase);
    const float2 v22b = *(const float2*)(o22 + obase + SW);

    v2f m11v[2], m12v[2], m22v[2];
    m11v[0] = (v2f){MSCALE * v11a.x, MSCALE * v11a.y};
    m11v[1] = (v2f){MSCALE * v11b.x, MSCALE * v11b.y};
    m12v[0] = (v2f){MSCALE * (v12a.x + v21a.x), MSCALE * (v12a.y + v21a.y)};
    m12v[1] = (v2f){MSCALE * (v12b.x + v21b.x), MSCALE * (v12b.y + v21b.y)};
    m22v[0] = (v2f){MSCALE * v22a.x, MSCALE * v22a.y};
    m22v[1] = (v2f){MSCALE * v22b.x, MSCALE * v22b.y};

    v2f sumwv[2] = {(v2f){0.f,0.f}, (v2f){0.f,0.f}};
    v2f acc0v[2] = {(v2f){0.f,0.f}, (v2f){0.f,0.f}};
    v2f acc1v[2] = {(v2f){0.f,0.f}, (v2f){0.f,0.f}};
    v2f acc2v[2] = {(v2f){0.f,0.f}, (v2f){0.f,0.f}};

    // COLK: one (a,row,column) contribution to all 4 subpixels.
    // Scalar Sterbenz-exact setup; packed (sx-pair) inner math:
    //   u = dx*m11 + dy*m12   (pk_mul + pk_fma: same rounding as scalar R8)
    //   d = dx*u   + dy2*m22  (pk_mul + pk_fma)
    // q_ pre-masked for column bounds; w fixups for the 2 runtime masks.
#define COLK(or_, oc_, q_, a0_, a1_, a2_, f2x_, IS_L, NEED_VY)                \
    {                                                                         \
        const float posr = fmaf(or_, 2.0f, rowf);                             \
        const float dy0v = posr - yf0;                                        \
        const float dy1v = dy0v - 1.0f;                                       \
        const float posc = fmaf(oc_, 2.0f, f2x_);                             \
        const float dx0v = posc - xf0;                                        \
        const float dx1v = dx0v - 1.0f;                                       \
        const v2f dxv = (v2f){dx0v, dx1v};                                    \
        const bool vx1 = !(IS_L) || (dx1v >= -RADIUS);                        \
        const bool vyb = !(NEED_VY) || (dy1v >= -RADIUS);                     \
        _Pragma("unroll")                                                     \
        for (int sy = 0; sy < 2; ++sy) {                                      \
            const float dyv = sy ? dy1v : dy0v;                               \
            const float dy2 = dyv * dyv;                                      \
            const v2f dyb = (v2f){dyv, dyv};                                  \
            const v2f d2b = (v2f){dy2, dy2};                                  \
            const v2f u = __builtin_elementwise_fma(dyb, m12v[sy],            \
                                                    dxv * m11v[sy]);          \
            const v2f d = __builtin_elementwise_fma(dxv, u,                   \
                                                    d2b * m22v[sy]);          \
            v2f w;                                                            \
            w.x = __builtin_amdgcn_exp2f(-d.x) * (q_);                        \
            w.y = __builtin_amdgcn_exp2f(-d.y) * (q_);                        \
            if (IS_L)                w.y = vx1 ? w.y : 0.0f;                  \
            if (NEED_VY && sy == 1) { w.x = vyb ? w.x : 0.0f;                 \
                                      w.y = vyb ? w.y : 0.0f; }               \
            sumwv[sy] += w;                                                   \
            acc0v[sy] = __builtin_elementwise_fma(w, (v2f){a0_, a0_},         \
                                                  acc0v[sy]);                 \
            acc1v[sy] = __builtin_elementwise_fma(w, (v2f){a1_, a1_},         \
                                                  acc1v[sy]);                 \
            acc2v[sy] = __builtin_elementwise_fma(w, (v2f){a2_, a2_},         \
                                                  acc2v[sy]);                 \
        }                                                                     \
    }

    #pragma unroll
    for (int ai = 0; ai < 2; ++ai) {
        const int a = af0 + ai;   // wave-uniform scalar
        const float* offbR = offsets + (size_t)(a * NB + nn) * 2 * HW;
        const float* offbC = offbR + HW;
        const float* qb    = qs   + (size_t)(a * NB + nn) * HW;
        const float* ab0   = alts + (size_t)(a * NB + nn) * CH * HW;
        const float* ab1   = ab0 + HW;
        const float* ab2   = ab0 + 2 * HW;

        #pragma unroll
        for (int dr = 0; dr < 3; ++dr) {        // dr = di + 1
            if (dr == 0 && y0 == 0) continue;   // scalar uniform skip
            if (dr == 2 && y0 == H - 1) continue;
            const int ro = (dr - 1) * W;        // scalar row offset
            const float* pR = offbR + ro;
            const float* pC = offbC + ro;
            const float* pQ = qb + ro;
            const float* p0 = ab0 + ro;
            const float* p1 = ab1 + ro;
            const float* p2 = ab2 + ro;
            const float rowf = (float)(2 * (y0 + dr - 1));

            // 18 batched scalar gathers (saddr + {iL,iC,iR})
            const float orL = pR[iL], orC = pR[iC], orR = pR[iR];
            const float ocL = pC[iL], ocC = pC[iC], ocR = pC[iR];
            const float qL  = pQ[iL], qC  = pQ[iC], qR  = pQ[iR];
            const float aL0 = p0[iL], aC0 = p0[iC], aR0 = p0[iR];
            const float aL1 = p1[iL], aC1 = p1[iC], aR1 = p1[iR];
            const float aL2 = p2[iL], aC2 = p2[iC], aR2 = p2[iR];

            // column-bounds masks folded into q (once, not per subpixel)
            const float qLm = bL ? qL : 0.0f;
            const float qRm = bR ? qR : 0.0f;

            const bool needvy = (dr == 0);
            COLK(orL, ocL, qLm, aL0, aL1, aL2, f2xL, true,  needvy)
            COLK(orC, ocC, qC,  aC0, aC1, aC2, f2xC, false, needvy)
            COLK(orR, ocR, qRm, aR0, aR1, aR2, f2xR, false, needvy)
        }
    }
#undef COLK

    // cross-fpair reduction: fpair 1 writes 16 floats/pixel, fpair 0 sums+stores
    if (fpair == 1) {
        float* r = &red[pix * 17];
        #pragma unroll
        for (int sy = 0; sy < 2; ++sy) {
            r[sy*8+0] = sumwv[sy].x; r[sy*8+1] = sumwv[sy].y;
            r[sy*8+2] = acc0v[sy].x; r[sy*8+3] = acc0v[sy].y;
            r[sy*8+4] = acc1v[sy].x; r[sy*8+5] = acc1v[sy].y;
            r[sy*8+6] = acc2v[sy].x; r[sy*8+7] = acc2v[sy].y;
        }
    }
    __syncthreads();
    if (fpair == 0) {
        const float* r = &red[pix * 17];
        #pragma unroll
        for (int sy = 0; sy < 2; ++sy) {
            sumwv[sy].x += r[sy*8+0]; sumwv[sy].y += r[sy*8+1];
            acc0v[sy].x += r[sy*8+2]; acc0v[sy].y += r[sy*8+3];
            acc1v[sy].x += r[sy*8+4]; acc1v[sy].y += r[sy*8+5];
            acc2v[sy].x += r[sy*8+6]; acc2v[sy].y += r[sy*8+7];
        }
        const size_t ob = (size_t)(nn * CH) * SHW + (size_t)(2 * y0) * SW + 2 * x0;
        #pragma unroll
        for (int sy = 0; sy < 2; ++sy) {
            const float i0 = 1.0f / sumwv[sy].x;
            const float i1 = 1.0f / sumwv[sy].y;
            *(float2*)(out + ob + (size_t)sy * SW) =
                make_float2(acc0v[sy].x * i0, acc0v[sy].y * i1);
            *(float2*)(out + ob + (size_t)sy * SW + SHW) =
                make_float2(acc1v[sy].x * i0, acc1v[sy].y * i1);
            *(float2*)(out + ob + (size_t)sy * SW + 2 * SHW) =
                make_float2(acc2v[sy].x * i0, acc2v[sy].y * i1);
        }
    }
}

extern "C" void kernel_launch(void* const* d_in, const int* in_sizes, int n_in,
                              void* d_out, int out_size, void* d_ws, size_t ws_size,
                              hipStream_t stream) {
    const float* alts    = (const float*)d_in[0];
    const float* offsets = (const float*)d_in[1];
    const float* qs      = (const float*)d_in[2];
    const float* o11     = (const float*)d_in[3];
    const float* o12     = (const float*)d_in[4];
    const float* o21     = (const float*)d_in[5];
    const float* o22     = (const float*)d_in[6];
    float* out = (float*)d_out;

    const int total_threads = NB * H * W * 2;   // 524,288
    const int block = 256;
    const int grid  = total_threads / block;    // 2048
    superresolve_kernel<<<grid, block, 0, stream>>>(alts, offsets, qs,
                                                    o11, o12, o21, o22, out);
}

// Round 13
// 24.039 us; speedup vs baseline: 1.0307x; 1.0307x over previous
//
#include <hip/hip_runtime.h>

// SuperResolve: A=4 frames, n=4, c=3, h=w=256, S=2 -> out (4,3,512,512) fp32
// R13: 4-way wave split by (fpair x subpixel-row). Block = 256 thr = 4 waves
// over the SAME 64 LR pixels (quarter row): wave w -> fpair = w>>1 (frames
// {0,1}/{2,3}), syh = w&1 (output sub-row 2*y0+syh). Per-thread state:
// 8 accs + 6 matrix consts + ~18 transients ~= 50 VGPR -> (256,8) pins
// 8 waves/SIMD WITHOUT compression (R3/R9 caps failed because natural state
// was way over; here it isn't). VALU/thread halves vs R8. Cost: sy-waves
// duplicate loads (2x VMEM total) -- R10 proved VMEM slack; dup hits L1.
// R6: SGPR plane bases. R8: raw v_exp_f32, q-premask, no dist clamp
// (max 17.6 < 20). R9: dy/dx pos-then-subtract (Sterbenz, mask bit-exact).
// R10: VMEM count not binding. R12: fp32 packing null.

#define AF      4
#define NB      4
#define CH      3
#define H       256
#define W       256
#define SH      512
#define SW      512
#define HW      (H*W)
#define SHW     (SH*SW)
#define RADIUS  4.0f
// 0.25 (LR displacement scaling) * 0.5*log2(e): weight = exp2(-dist')
#define MSCALE  0.18033688011112042f

__global__ __launch_bounds__(256, 8) void superresolve_kernel(
    const float* __restrict__ alts,     // [AF][NB][CH][H][W]
    const float* __restrict__ offsets,  // [AF][NB][2][H][W]
    const float* __restrict__ qs,      // [AF][NB][H][W]
    const float* __restrict__ o11,      // [NB][SH][SW]
    const float* __restrict__ o12,
    const float* __restrict__ o21,
    const float* __restrict__ o22,
    float* __restrict__ out)            // [NB][CH][SH][SW]
{
    __shared__ float red[2 * 64 * 9];   // 4.6 KB; stride 9 (odd): conflict-free

    const int tid  = threadIdx.x;
    const int wv   = tid >> 6;
    const int lane = tid & 63;
    const int fpair = wv >> 1;          // 0: frames {0,1}; 1: {2,3}
    const int syh   = wv & 1;           // output sub-row

    // bijective XCD swizzle over 4096 blocks (4096 % 8 == 0)
    const int bid = blockIdx.x;
    const int swz = (bid & 7) * 512 + (bid >> 3);
    // swz bits: [1:0] x-quarter, [9:2] y0, [11:10] nn
    const int x0 = ((swz & 3) << 6) + lane;
    const int y0  = __builtin_amdgcn_readfirstlane((swz >> 2) & (H - 1));
    const int nn  = __builtin_amdgcn_readfirstlane(swz >> 10);
    const int af0 = __builtin_amdgcn_readfirstlane(fpair << 1);
    const int sy  = __builtin_amdgcn_readfirstlane(syh);

    const bool bL = (x0 > 0);
    const bool bR = (x0 < W - 1);
    const int  xL = bL ? x0 - 1 : 0;
    const int  xR = bR ? x0 + 1 : W - 1;
    const int  iL = y0 * W + xL;
    const int  iC = y0 * W + x0;
    const int  iR = y0 * W + xR;
    const float f2xL = (float)(2 * xL);
    const float f2xC = (float)(2 * x0);
    const float f2xR = (float)(2 * xR);
    const float xf0  = f2xC;
    const float yfS  = (float)(2 * y0 + sy);    // this wave's output row

    // o-matrices for this wave's sub-row only (float2 loads, coalesced)
    const int obase = (nn * SH + 2 * y0 + sy) * SW + 2 * x0;
    const float2 v11 = *(const float2*)(o11 + obase);
    const float2 v12 = *(const float2*)(o12 + obase);
    const float2 v21 = *(const float2*)(o21 + obase);
    const float2 v22 = *(const float2*)(o22 + obase);

    // 6 per-subpixel consts (sx = 0,1)
    const float m11x = MSCALE * v11.x, m11y = MSCALE * v11.y;
    const float m12x = MSCALE * (v12.x + v21.x), m12y = MSCALE * (v12.y + v21.y);
    const float m22x = MSCALE * v22.x, m22y = MSCALE * v22.y;

    // 8 accumulators: [sx] x {sumw, c0, c1, c2}
    float sumw0 = 0.f, sumw1 = 0.f;
    float a00 = 0.f, a01 = 0.f;     // ch0 sx0/sx1
    float a10 = 0.f, a11 = 0.f;     // ch1
    float a20 = 0.f, a21 = 0.f;     // ch2

    // COLK: one (a,row,column) contribution to this wave's 2 subpixels.
    // Sterbenz-exact dy/dx; q_ pre-masked for column bounds; no dist clamp.
    // vy mask only possible at (dr==0, sy==1): dy = 2(rn-y0)+2off-sy.
#define COLK(or_, oc_, q_, a0_, a1_, a2_, f2x_, IS_L, DR0)                    \
    {                                                                         \
        const float posr = fmaf(or_, 2.0f, rowf);                             \
        const float dyv  = posr - yfS;                                        \
        const float posc = fmaf(oc_, 2.0f, f2x_);                             \
        const float dx0v = posc - xf0;                                        \
        const float dx1v = dx0v - 1.0f;                                       \
        const float dy2  = dyv * dyv;                                         \
        const float u0 = fmaf(dyv, m12x, dx0v * m11x);                        \
        const float d0 = fmaf(dx0v, u0, dy2 * m22x);                          \
        const float u1 = fmaf(dyv, m12y, dx1v * m11y);                        \
        const float d1 = fmaf(dx1v, u1, dy2 * m22y);                          \
        float w0 = __builtin_amdgcn_exp2f(-d0) * (q_);                        \
        float w1 = __builtin_amdgcn_exp2f(-d1) * (q_);                        \
        if (IS_L) w1 = (dx1v >= -RADIUS) ? w1 : 0.0f;                         \
        if (DR0 && sy) {                                                      \
            const bool vy = (dyv >= -RADIUS);                                 \
            w0 = vy ? w0 : 0.0f;                                              \
            w1 = vy ? w1 : 0.0f;                                              \
        }                                                                     \
        sumw0 += w0;            sumw1 += w1;                                  \
        a00 = fmaf(w0, a0_, a00); a01 = fmaf(w1, a0_, a01);                   \
        a10 = fmaf(w0, a1_, a10); a11 = fmaf(w1, a1_, a11);                   \
        a20 = fmaf(w0, a2_, a20); a21 = fmaf(w1, a2_, a21);                   \
    }

    #pragma unroll
    for (int ai = 0; ai < 2; ++ai) {
        const int a = af0 + ai;   // wave-uniform scalar
        const float* offbR = offsets + (size_t)(a * NB + nn) * 2 * HW;
        const float* offbC = offbR + HW;
        const float* qb    = qs   + (size_t)(a * NB + nn) * HW;
        const float* ab0   = alts + (size_t)(a * NB + nn) * CH * HW;
        const float* ab1   = ab0 + HW;
        const float* ab2   = ab0 + 2 * HW;

        #pragma unroll
        for (int dr = 0; dr < 3; ++dr) {        // dr = di + 1
            if (dr == 0 && y0 == 0) continue;   // scalar uniform skip
            if (dr == 2 && y0 == H - 1) continue;
            const int ro = (dr - 1) * W;        // scalar row offset
            const float* pR = offbR + ro;
            const float* pC = offbC + ro;
            const float* pQ = qb + ro;
            const float* p0 = ab0 + ro;
            const float* p1 = ab1 + ro;
            const float* p2 = ab2 + ro;
            const float rowf = (float)(2 * (y0 + dr - 1));

            // 18 batched scalar gathers (saddr + {iL,iC,iR})
            const float orL = pR[iL], orC = pR[iC], orR = pR[iR];
            const float ocL = pC[iL], ocC = pC[iC], ocR = pC[iR];
            const float qL  = pQ[iL], qC  = pQ[iC], qR  = pQ[iR];
            const float aL0 = p0[iL], aC0 = p0[iC], aR0 = p0[iR];
            const float aL1 = p1[iL], aC1 = p1[iC], aR1 = p1[iR];
            const float aL2 = p2[iL], aC2 = p2[iC], aR2 = p2[iR];

            // column-bounds masks folded into q (once, not per subpixel)
            const float qLm = bL ? qL : 0.0f;
            const float qRm = bR ? qR : 0.0f;

            const bool dr0 = (dr == 0);
            COLK(orL, ocL, qLm, aL0, aL1, aL2, f2xL, true,  dr0)
            COLK(orC, ocC, qC,  aC0, aC1, aC2, f2xC, false, dr0)
            COLK(orR, ocR, qRm, aR0, aR1, aR2, f2xR, false, dr0)
        }
    }
#undef COLK

    // cross-fpair reduction per syh: fpair 1 writes 8 floats, fpair 0 sums+stores
    if (fpair == 1) {
        float* r = &red[(syh * 64 + lane) * 9];
        r[0] = sumw0; r[1] = sumw1;
        r[2] = a00;   r[3] = a01;
        r[4] = a10;   r[5] = a11;
        r[6] = a20;   r[7] = a21;
    }
    __syncthreads();
    if (fpair == 0) {
        const float* r = &red[(syh * 64 + lane) * 9];
        sumw0 += r[0]; sumw1 += r[1];
        a00 += r[2];   a01 += r[3];
        a10 += r[4];   a11 += r[5];
        a20 += r[6];   a21 += r[7];

        const float i0 = 1.0f / sumw0;
        const float i1 = 1.0f / sumw1;
        const size_t ob = (size_t)(nn * CH) * SHW
                        + (size_t)(2 * y0 + sy) * SW + 2 * x0;
        *(float2*)(out + ob)           = make_float2(a00 * i0, a01 * i1);
        *(float2*)(out + ob + SHW)     = make_float2(a10 * i0, a11 * i1);
        *(float2*)(out + ob + 2*SHW)   = make_float2(a20 * i0, a21 * i1);
    }
}

extern "C" void kernel_launch(void* const* d_in, const int* in_sizes, int n_in,
                              void* d_out, int out_size, void* d_ws, size_t ws_size,
                              hipStream_t stream) {
    const float* alts    = (const float*)d_in[0];
    const float* offsets = (const float*)d_in[1];
    const float* qs      = (const float*)d_in[2];
    const float* o11     = (const float*)d_in[3];
    const float* o12     = (const float*)d_in[4];
    const float* o21     = (const float*)d_in[5];
    const float* o22     = (const float*)d_in[6];
    float* out = (float*)d_out;

    const int total_threads = NB * H * W * 4;   // 1,048,576
    const int block = 256;
    const int grid  = total_threads / block;    // 4096
    superresolve_kernel<<<grid, block, 0, stream>>>(alts, offsets, qs,
                                                    o11, o12, o21, o22, out);
}